// Round 2
// baseline (976.403 us; speedup 1.0000x reference)
//
#include <hip/hip_runtime.h>
#include <hip/hip_fp16.h>

#define Bb 64
#define Nn 1024
#define Cc 558
#define CP1 559
#define CPAD 560
#define ITERS 20
#define BLKS_PER_B 4
#define WAVES 8
#define RPW 32                 /* rows per wave */
#define POLL_CAP (1 << 22)

#if __has_builtin(__builtin_amdgcn_rcpf)
#define RCP(x) __builtin_amdgcn_rcpf(x)
#else
#define RCP(x) (1.0f / (x))
#endif

__device__ __forceinline__ float wave_sum(float v) {
#pragma unroll
    for (int off = 32; off > 0; off >>= 1) v += __shfl_xor(v, off, 64);
    return v;
}

__device__ __forceinline__ void g_store(float* p, float v) {
    __hip_atomic_store(p, v, __ATOMIC_RELAXED, __HIP_MEMORY_SCOPE_AGENT);
}
__device__ __forceinline__ float g_load(const float* p) {
    return __hip_atomic_load(p, __ATOMIC_RELAXED, __HIP_MEMORY_SCOPE_AGENT);
}

// ---- K1: mask-format detect + per-batch mask processing + class-NLL gather ----
__global__ __launch_bounds__(256) void k1_batch(const float* __restrict__ logits,
        const int* __restrict__ labels, const void* __restrict__ maskp,
        float* __restrict__ A_part, float* __restrict__ inv_nvis,
        unsigned char* __restrict__ visc, int* __restrict__ ctr) {
    const int b = blockIdx.x, tid = threadIdx.x;
    __shared__ int sF, sB;
    __shared__ int cs_[256];
    __shared__ float red[256];
    if (tid == 0) { sF = 0; sB = 0; }
    __syncthreads();
    {
        const unsigned int* mw = (const unsigned int*)maskp;
        int lF = 0, lB = 0;
        for (int i = tid; i < (Bb * Nn) / 4; i += 256) {
            unsigned w = mw[i];
            if (w == 0x3F800000u) lF = 1;
            else if (w > 1u) lB = 1;
        }
        if (lF) sF = 1;
        if (lB) sB = 1;
    }
    __syncthreads();
    const int mode = sF ? 2 : (sB ? 1 : 0);   // 0=int32, 1=bool bytes, 2=float32
    int v[4]; int local = 0;
#pragma unroll
    for (int j = 0; j < 4; ++j) {
        const int n = tid * 4 + j;
        const int idx = b * Nn + n;
        int m;
        if (mode == 1)      m = ((const unsigned char*)maskp)[idx] != 0;
        else if (mode == 2) m = ((const float*)maskp)[idx] != 0.f;
        else                m = ((const int*)maskp)[idx] != 0;
        v[j] = m; local += m;
    }
    cs_[tid] = local;
    __syncthreads();
    for (int off = 1; off < 256; off <<= 1) {   // inclusive scan
        int x = 0;
        if (tid >= off) x = cs_[tid - off];
        __syncthreads();
        cs_[tid] += x;
        __syncthreads();
    }
    const int nvis = cs_[255];
    int run = cs_[tid] - local;                  // exclusive prefix
    float nllsum = 0.f;
#pragma unroll
    for (int j = 0; j < 4; ++j) {
        const int n = tid * 4 + j;
        run += v[j];
        visc[b * Nn + n] = (unsigned char)v[j];
        if (v[j]) {
            const int tgt = labels[b * Nn + (run - 1)];
            nllsum -= logits[((size_t)(b * Nn + n)) * Cc + tgt];
        }
    }
    red[tid] = nllsum;
    __syncthreads();
    for (int off = 128; off > 0; off >>= 1) {
        if (tid < off) red[tid] += red[tid + off];
        __syncthreads();
    }
    if (tid == 0) {
        A_part[b] = red[0];
        inv_nvis[b] = 1.f / (float)nvis;
        __hip_atomic_store(&ctr[b], 0, __ATOMIC_RELAXED, __HIP_MEMORY_SCOPE_AGENT);
    }
}

// ---- K_MAIN: persistent — softmax -> 20 reg-resident Sinkhorn iters -> entropy ----
// 256 blocks (exact CU fit, all co-resident), 512 threads, 4 blocks per batch.
__global__ __launch_bounds__(512, 2) void k_main(
        const float* __restrict__ logits, const float* __restrict__ dustbin,
        const unsigned char* __restrict__ visc, const float* __restrict__ inv_nvis,
        float* __restrict__ cs, int* __restrict__ ctr, float* __restrict__ eu_g,
        float* __restrict__ lse_part, float* __restrict__ ent_part) {
    __shared__ float partl[WAVES][CPAD];
    __shared__ float evl[CPAD];
    __shared__ float redL[WAVES], redE[WAVES];
    const int g = blockIdx.x;
    const int b = ((g & 7) << 3) | (g >> 5);      // XCD-grouped: 4 blocks of a batch on one XCD
    const int p = (g >> 3) & 3;
    const int tid = threadIdx.x, wave = tid >> 6, lane = tid & 63;
    const int row0 = (b << 10) + (p << 8) + (wave << 5);
    const float dustp = __expf(dustbin[0]);
    const float invn = inv_nvis[b];
    const int tl = lane < 46;

    const uint4 vA = *(const uint4*)(visc + row0);
    const uint4 vB = *(const uint4*)(visc + row0 + 16);
    unsigned vw[8] = {vA.x, vA.y, vA.z, vA.w, vB.x, vB.y, vB.z, vB.w};
#define VIS(r) ((vw[(r) >> 2] >> (((r) & 3) << 3)) & 0xffu)

    __half2 px[RPW][4];
    float pt[RPW];
    float lsesum = 0.f;

    // ---------- softmax into registers (logits read ONCE) ----------
#pragma unroll
    for (int r = 0; r < RPW; ++r) {
        if (__builtin_amdgcn_readfirstlane(VIS(r))) {
            const float* rowp = logits + (size_t)(row0 + r) * Cc;
            const int c0 = lane << 3;
            float e0 = __expf(rowp[c0 + 0]), e1 = __expf(rowp[c0 + 1]);
            float e2 = __expf(rowp[c0 + 2]), e3 = __expf(rowp[c0 + 3]);
            float e4 = __expf(rowp[c0 + 4]), e5 = __expf(rowp[c0 + 5]);
            float e6 = __expf(rowp[c0 + 6]), e7 = __expf(rowp[c0 + 7]);
            float et = tl ? __expf(rowp[512 + lane]) : 0.f;
            float s = wave_sum(e0 + e1 + e2 + e3 + e4 + e5 + e6 + e7 + et);
            const float inv = RCP(s);
            px[r][0] = __floats2half2_rn(e0 * inv, e1 * inv);
            px[r][1] = __floats2half2_rn(e2 * inv, e3 * inv);
            px[r][2] = __floats2half2_rn(e4 * inv, e5 * inv);
            px[r][3] = __floats2half2_rn(e6 * inv, e7 * inv);
            pt[r] = et * inv;
            lsesum += __logf(s);                 // same value on all lanes; lane0 used later
        } else {
            px[r][0] = px[r][1] = px[r][2] = px[r][3] = __floats2half2_rn(0.f, 0.f);
            pt[r] = 0.f;
        }
    }

    // ---------- 20 Sinkhorn iterations ----------
    float evr[8], evt, evd;
    for (int t = 0; t < ITERS; ++t) {
        if (t == 0) {
#pragma unroll
            for (int k = 0; k < 8; ++k) evr[k] = 1.f;
            evt = 1.f; evd = 1.f;
        } else {
            const float* CSr = cs + (size_t)(((t - 1) & 1) * Bb + b) * (BLKS_PER_B * CPAD);
            for (int c = tid; c < CP1; c += 512) {
                float s = g_load(CSr + c) + g_load(CSr + CPAD + c)
                        + g_load(CSr + 2 * CPAD + c) + g_load(CSr + 3 * CPAD + c);
                evl[c] = RCP(559.f * s);
            }
            __syncthreads();
#pragma unroll
            for (int k = 0; k < 8; ++k) evr[k] = evl[(lane << 3) + k];
            evt = tl ? evl[512 + lane] : 0.f;
            evd = evl[558];
        }
        float pc0 = 0.f, pc1 = 0.f, pc2 = 0.f, pc3 = 0.f;
        float pc4 = 0.f, pc5 = 0.f, pc6 = 0.f, pc7 = 0.f;
        float pct = 0.f, pcd = 0.f;
        const float dd = dustp * evd;
#pragma unroll
        for (int r = 0; r < RPW; ++r) {
            if (__builtin_amdgcn_readfirstlane(VIS(r))) {
                const float2 f0 = __half22float2(px[r][0]);
                const float2 f1 = __half22float2(px[r][1]);
                const float2 f2 = __half22float2(px[r][2]);
                const float2 f3 = __half22float2(px[r][3]);
                float s = pt[r] * evt
                        + f0.x * evr[0] + f0.y * evr[1] + f1.x * evr[2] + f1.y * evr[3]
                        + f2.x * evr[4] + f2.y * evr[5] + f3.x * evr[6] + f3.y * evr[7];
                s = wave_sum(s) + dd;
                const float euv = invn * RCP(s);
                if (t == ITERS - 1 && lane == 0) eu_g[row0 + r] = euv;
                pc0 += f0.x * euv; pc1 += f0.y * euv; pc2 += f1.x * euv; pc3 += f1.y * euv;
                pc4 += f2.x * euv; pc5 += f2.y * euv; pc6 += f3.x * euv; pc7 += f3.y * euv;
                pct += pt[r] * euv; pcd += euv;
            } else if (t == ITERS - 1 && lane == 0) {
                eu_g[row0 + r] = 0.f;
            }
        }
        const int cb = lane << 3;
        partl[wave][cb + 0] = pc0; partl[wave][cb + 1] = pc1;
        partl[wave][cb + 2] = pc2; partl[wave][cb + 3] = pc3;
        partl[wave][cb + 4] = pc4; partl[wave][cb + 5] = pc5;
        partl[wave][cb + 6] = pc6; partl[wave][cb + 7] = pc7;
        if (tl) partl[wave][512 + lane] = pct;
        if (lane == 0) partl[wave][558] = pcd * dustp;
        __syncthreads();
        float* CSw = cs + ((size_t)((t & 1) * Bb + b) * BLKS_PER_B + p) * CPAD;
        for (int c = tid; c < CP1; c += 512) {
            float s = partl[0][c] + partl[1][c] + partl[2][c] + partl[3][c]
                    + partl[4][c] + partl[5][c] + partl[6][c] + partl[7][c];
            g_store(CSw + c, s);
        }
        __syncthreads();   // drains vmcnt: all this block's CS stores complete
        if (tid == 0) {
            __hip_atomic_fetch_add(&ctr[b], 1, __ATOMIC_RELEASE, __HIP_MEMORY_SCOPE_AGENT);
            const int target = BLKS_PER_B * (t + 1);
            int polls = 0;
            while (__hip_atomic_load(&ctr[b], __ATOMIC_ACQUIRE, __HIP_MEMORY_SCOPE_AGENT) < target) {
                __builtin_amdgcn_s_sleep(1);
                if (++polls > POLL_CAP) break;   // fail-visible, never hang
            }
        }
        __syncthreads();
    }

    // ---------- final ev + entropy ----------
    {
        const float* CSr = cs + (size_t)(((ITERS - 1) & 1) * Bb + b) * (BLKS_PER_B * CPAD);
        for (int c = tid; c < CP1; c += 512) {
            float s = g_load(CSr + c) + g_load(CSr + CPAD + c)
                    + g_load(CSr + 2 * CPAD + c) + g_load(CSr + 3 * CPAD + c);
            evl[c] = RCP(559.f * s);
        }
        __syncthreads();
#pragma unroll
        for (int k = 0; k < 8; ++k) evr[k] = evl[(lane << 3) + k];
        evt = tl ? evl[512 + lane] : 0.f;
    }
    float acc = 0.f;
#pragma unroll
    for (int r = 0; r < RPW; ++r) {
        if (__builtin_amdgcn_readfirstlane(VIS(r))) {
            const float euv = eu_g[row0 + r];
            const float2 f0 = __half22float2(px[r][0]);
            const float2 f1 = __half22float2(px[r][1]);
            const float2 f2 = __half22float2(px[r][2]);
            const float2 f3 = __half22float2(px[r][3]);
            float P;
            P = f0.x * euv * evr[0]; acc -= P * __logf(P + 1e-8f);
            P = f0.y * euv * evr[1]; acc -= P * __logf(P + 1e-8f);
            P = f1.x * euv * evr[2]; acc -= P * __logf(P + 1e-8f);
            P = f1.y * euv * evr[3]; acc -= P * __logf(P + 1e-8f);
            P = f2.x * euv * evr[4]; acc -= P * __logf(P + 1e-8f);
            P = f2.y * euv * evr[5]; acc -= P * __logf(P + 1e-8f);
            P = f3.x * euv * evr[6]; acc -= P * __logf(P + 1e-8f);
            P = f3.y * euv * evr[7]; acc -= P * __logf(P + 1e-8f);
            P = pt[r] * euv * evt;   acc -= P * __logf(P + 1e-8f);
        }
    }
    acc = wave_sum(acc);
    if (lane == 0) { redE[wave] = acc; redL[wave] = lsesum; }
    __syncthreads();
    if (tid == 0) {
        float eS = 0.f, lS = 0.f;
#pragma unroll
        for (int w = 0; w < WAVES; ++w) { eS += redE[w]; lS += redL[w]; }
        ent_part[(b << 2) | p] = eS;
        lse_part[(b << 2) | p] = lS;
    }
}

// ---- K4: combine ----
__global__ void k4_out(const float* __restrict__ A_part, const float* __restrict__ lse_part,
        const float* __restrict__ ent_part, const float* __restrict__ inv_nvis,
        float* __restrict__ out) {
    const int b = threadIdx.x;   // 64 threads = 1 wave
    float l = 0.f, e = 0.f;
#pragma unroll
    for (int p = 0; p < 4; ++p) { l += lse_part[(b << 2) | p]; e += ent_part[(b << 2) | p]; }
    float v = (A_part[b] + l) * inv_nvis[b] + 0.5f * e * inv_nvis[b];
    v = wave_sum(v);
    if (b == 0) out[0] = v * (1.f / 64.f);
}

extern "C" void kernel_launch(void* const* d_in, const int* in_sizes, int n_in,
                              void* d_out, int out_size, void* d_ws, size_t ws_size,
                              hipStream_t stream) {
    const float* logits = (const float*)d_in[0];
    const float* dustbin = (const float*)d_in[1];
    const int* labels = (const int*)d_in[2];
    const void* mask = d_in[3];
    float* out = (float*)d_out;

    char* ws = (char*)d_ws;
    size_t off = 0;
    float* cs = (float*)(ws + off);            off += 2ull * Bb * BLKS_PER_B * CPAD * 4;  // 1.15 MB
    int* ctr = (int*)(ws + off);               off += Bb * 4;
    float* eu_g = (float*)(ws + off);          off += (size_t)Bb * Nn * 4;
    unsigned char* visc = (unsigned char*)(ws + off); off += (size_t)Bb * Nn;
    float* inv_nvis = (float*)(ws + off);      off += Bb * 4;
    float* A_part = (float*)(ws + off);        off += Bb * 4;
    float* lse_part = (float*)(ws + off);      off += Bb * BLKS_PER_B * 4;
    float* ent_part = (float*)(ws + off);      off += Bb * BLKS_PER_B * 4;

    k1_batch<<<Bb, 256, 0, stream>>>(logits, labels, mask, A_part, inv_nvis, visc, ctr);
    k_main<<<Bb * BLKS_PER_B, 512, 0, stream>>>(logits, dustbin, visc, inv_nvis,
                                                cs, ctr, eu_g, lse_part, ent_part);
    k4_out<<<1, 64, 0, stream>>>(A_part, lse_part, ent_part, inv_nvis, out);
    (void)in_sizes; (void)n_in; (void)out_size; (void)ws_size;
}